// Round 18
// baseline (133.627 us; speedup 1.0000x reference)
//
#include <hip/hip_runtime.h>
#include <hip/hip_bf16.h>
#include <math.h>
#include <stdint.h>

#define HC 4
#define DIM 16384                  // hc*hidden
#define MIXN 24
#define NROWS 8192                 // B*S
#define KSPLIT 32                  // k-slices
#define KSL 512                    // k per slice
#define NSTEPS 16                  // MFMA k-steps per slice
#define NSTREAM 16                 // row streams
#define ROWS_PER_STREAM 512
#define NTILES 32                  // 16-row tiles per block
#define NBUF 2                     // s_a ring buffers (77 KB total LDS -> 2 blocks/CU)
#define THREADS1 512
#define WREC 32                    // padded floats per (row, ks) record
#define HC_EPS 1e-5f
#define NORM_EPS 1e-6f

#define PRE_OFF 0
#define POST_OFF (NROWS * HC)
#define COMB_OFF (2 * NROWS * HC)

typedef float f32x4 __attribute__((ext_vector_type(4)));
typedef float accf4 __attribute__((ext_vector_type(4)));
typedef short bf16x8 __attribute__((ext_vector_type(8)));
typedef short bf16x4 __attribute__((ext_vector_type(4)));

__device__ __forceinline__ short f2bf(float x) {
    union { __hip_bfloat16 h; short s; } u;
    u.h = __float2bfloat16(x);
    return u.s;
}

// ---------------- kernel 1 ----------------
// R17's validated pipeline (contiguous 1KB A loads, 2 register ISSUE sets
// holding tiles t+2/t+3 in flight, swizzled fragment LDS) with NBUF=2 so
// LDS = 77 KB -> 2 blocks/CU: co-resident block streams through this
// block's serial phases. ws is [row][ks][32] so k2 can read coalesced.
__global__ __launch_bounds__(THREADS1) void hyper_k1(
    const float* __restrict__ hs,   // [NROWS][DIM]
    const float* __restrict__ fn,   // [MIXN][DIM]
    float* __restrict__ ws)         // [NROWS][KSPLIT][WREC]
{
    const int tid  = threadIdx.x;
    const int wave = tid >> 6;
    const int lane = tid & 63;
    const int l15  = lane & 15;
    const int kg   = lane >> 4;
    const int ks     = blockIdx.x & (KSPLIT - 1);
    const int stream = blockIdx.x >> 5;

    __shared__ __align__(16) short s_fn[2][NSTEPS][512];    // 32 KB B-fragments
    __shared__ __align__(16) short s_a[NBUF][NSTEPS][512];  // 32 KB A ring
    __shared__ float sC[8][400];                            // 12.8 KB partials

    // ---- fill s_fn (R15/16/17-validated 4-pass mapping for KSL=512) ----
    #pragma unroll 1
    for (int p = 0; p < 4; ++p) {
        const int idx  = p * THREADS1 + tid;
        const int kgf  = idx & 3;
        const int s    = (idx >> 2) & 15;
        const int c    = (idx >> 6) & 15;
        const int tile = idx >> 10;
        const int col  = tile ? (c + 8) : c;
        const float* g = fn + (size_t)col * DIM + ks * KSL + s * 32 + kgf * 8;
        const f32x4 v0 = *(const f32x4*)g;
        const f32x4 v1 = *(const f32x4*)(g + 4);
        bf16x8 b = { f2bf(v0.x), f2bf(v0.y), f2bf(v0.z), f2bf(v0.w),
                     f2bf(v1.x), f2bf(v1.y), f2bf(v1.z), f2bf(v1.w) };
        *(bf16x8*)&s_fn[tile][s][(kgf * 16 + c) * 8] = b;
    }
    __syncthreads();

    // stage-lane decomposition (R14-validated)
    const int st_slo = lane >> 3;
    const int st_kg  = (lane >> 1) & 3;
    const int st_e   = (lane & 1) * 4;
    const int sr0 = 2 * wave, sr1 = 2 * wave + 1;

    // two register ISSUE sets; set parity = tile & 1
    f32x4 RA0, RA1, RA2, RA3;
    f32x4 RB0, RB1, RB2, RB3;

#define ISSUE(P0, P1, P2, P3, T) do { \
    const float* g0 = hs + (size_t)(stream * ROWS_PER_STREAM + (T) * 16 + sr0) * DIM + ks * KSL; \
    const float* g1 = hs + (size_t)(stream * ROWS_PER_STREAM + (T) * 16 + sr1) * DIM + ks * KSL; \
    P0 = *(const f32x4*)(g0 +   0 + lane * 4); \
    P1 = *(const f32x4*)(g0 + 256 + lane * 4); \
    P2 = *(const f32x4*)(g1 +   0 + lane * 4); \
    P3 = *(const f32x4*)(g1 + 256 + lane * 4); \
} while (0)

#define WR1(BUF, Rj, r, j) do { \
    const int s_ = (j) * 8 + st_slo; \
    int byte_ = ((s_ * 64 + st_kg * 16 + (r)) * 16) + st_e * 2; \
    byte_ ^= ((s_ & 7) << 4); \
    bf16x4 v_ = { f2bf(Rj.x), f2bf(Rj.y), f2bf(Rj.z), f2bf(Rj.w) }; \
    *(bf16x4*)((char*)(&s_a[BUF][0][0]) + byte_) = v_; \
} while (0)

#define WRALL(BUF, P0, P1, P2, P3) do { \
    WR1(BUF, P0, sr0, 0); WR1(BUF, P1, sr0, 1); \
    WR1(BUF, P2, sr1, 0); WR1(BUF, P3, sr1, 1); \
} while (0)

    // prologue: tiles 0,1 issued; tile 0 staged into buf 0; tile 2 issued
    ISSUE(RA0, RA1, RA2, RA3, 0);
    ISSUE(RB0, RB1, RB2, RB3, 1);
    WRALL(0, RA0, RA1, RA2, RA3);        // waits set A only (oldest in queue)
    ISSUE(RA0, RA1, RA2, RA3, 2);

    int buf = 0;
    #pragma unroll 2
    for (int t = 0; t < NTILES; ++t) {
        asm volatile("s_waitcnt lgkmcnt(0)" ::: "memory");
        __builtin_amdgcn_s_barrier();            // raw: in-flight loads survive
        __builtin_amdgcn_sched_barrier(0);

        // ---- compute: this wave's 2 k-steps of the 16-row tile ----
        accf4 acc0 = {0.f, 0.f, 0.f, 0.f};
        accf4 acc1 = {0.f, 0.f, 0.f, 0.f};
        accf4 accS = {0.f, 0.f, 0.f, 0.f};
        #pragma unroll
        for (int i = 0; i < 2; ++i) {
            const int s = wave * 2 + i;
            int ab = ((s * 64 + lane) * 16) ^ ((s & 7) << 4);
            const bf16x8 af = *(const bf16x8*)((const char*)(&s_a[buf][0][0]) + ab);
            const bf16x8 b0 = *(const bf16x8*)&s_fn[0][s][lane * 8];
            const bf16x8 b1 = *(const bf16x8*)&s_fn[1][s][lane * 8];
            acc0 = __builtin_amdgcn_mfma_f32_16x16x32_bf16(af, b0, acc0, 0, 0, 0);
            acc1 = __builtin_amdgcn_mfma_f32_16x16x32_bf16(af, b1, acc1, 0, 0, 0);
            accS = __builtin_amdgcn_mfma_f32_16x16x32_bf16(af, af, accS, 0, 0, 0);
        }

        // per-wave partials -> sC (C layout validated R11)
        #pragma unroll
        for (int i = 0; i < 4; ++i)
            sC[wave][(kg * 4 + i) * 25 + l15] = acc0[i];
        if (l15 >= 8) {
            #pragma unroll
            for (int i = 0; i < 4; ++i)
                sC[wave][(kg * 4 + i) * 25 + l15 + 8] = acc1[i];
        }
        #pragma unroll
        for (int i = 0; i < 4; ++i)
            if (l15 == kg * 4 + i) sC[wave][l15 * 25 + 24] = accS[i];

        asm volatile("s_waitcnt lgkmcnt(0)" ::: "memory");
        __builtin_amdgcn_s_barrier();
        __builtin_amdgcn_sched_barrier(0);

        // ---- reduce 8 waves -> ws[row][ks][WREC] (no atomics) ----
        if (tid < 400) {
            const int rr = tid / 25, c = tid % 25;
            const float v = sC[0][tid] + sC[1][tid] + sC[2][tid] + sC[3][tid]
                          + sC[4][tid] + sC[5][tid] + sC[6][tid] + sC[7][tid];
            const int row = stream * ROWS_PER_STREAM + t * 16 + rr;
            ws[((size_t)row * KSPLIT + ks) * WREC + c] = v;
        }

        // ---- WRALL(t+1) from older set, then ISSUE(t+3) into same set ----
        if (t + 1 < NTILES) {
            const int nbuf = buf ^ 1;
            if ((t & 1) == 0) {
                WRALL(nbuf, RB0, RB1, RB2, RB3);             // tile t+1 (set B)
                if (t + 3 < NTILES) ISSUE(RB0, RB1, RB2, RB3, t + 3);
            } else {
                WRALL(nbuf, RA0, RA1, RA2, RA3);             // tile t+1 (set A)
                if (t + 3 < NTILES) ISSUE(RA0, RA1, RA2, RA3, t + 3);
            }
        }
        buf ^= 1;
    }
#undef ISSUE
#undef WR1
#undef WRALL
}

// ---------------- kernel 2: parallel slice-reduce + epilogue ----------------
// One 32-lane group per row: thread ks reads its slice's 25 floats
// (contiguous, 128B-aligned record), width-32 butterfly, lane 0 epilogue.
// 1024 blocks -> full-chip read of the 32 MB ws.
__global__ __launch_bounds__(256) void hyper_k2(
    const float* __restrict__ ws,
    const float* __restrict__ base,
    const float* __restrict__ scale,
    float* __restrict__ out)
{
    const int tid = threadIdx.x;
    const int row = blockIdx.x * 8 + (tid >> 5);     // 8 rows per block
    const int ks  = tid & 31;

    float v[25];
    const float* w = ws + ((size_t)row * KSPLIT + ks) * WREC;
    #pragma unroll
    for (int c = 0; c < 25; ++c) v[c] = w[c];

    #pragma unroll
    for (int off = 16; off >= 1; off >>= 1)
        #pragma unroll
        for (int c = 0; c < 25; ++c) v[c] += __shfl_xor(v[c], off, 32);

    if (ks != 0) return;

    const float rs = 1.0f / sqrtf(v[24] * (1.0f / (float)DIM) + NORM_EPS);
    const float s0 = scale[0], s1 = scale[1], s2 = scale[2];

    #pragma unroll
    for (int i = 0; i < HC; ++i) {
        const float z = v[i] * rs * s0 + base[i];
        out[PRE_OFF + row * HC + i] = 1.0f / (1.0f + expf(-z)) + HC_EPS;
    }
    #pragma unroll
    for (int i = 0; i < HC; ++i) {
        const float z = v[HC + i] * rs * s1 + base[HC + i];
        out[POST_OFF + row * HC + i] = 2.0f / (1.0f + expf(-z));
    }

    float c[HC][HC];
    #pragma unroll
    for (int i = 0; i < HC; ++i) {
        float l[HC];
        #pragma unroll
        for (int j = 0; j < HC; ++j)
            l[j] = v[2 * HC + i * HC + j] * rs * s2 + base[2 * HC + i * HC + j];
        const float mx = fmaxf(fmaxf(l[0], l[1]), fmaxf(l[2], l[3]));
        float e[HC];
        float sum = 0.0f;
        #pragma unroll
        for (int j = 0; j < HC; ++j) { e[j] = expf(l[j] - mx); sum += e[j]; }
        const float inv = 1.0f / sum;
        #pragma unroll
        for (int j = 0; j < HC; ++j) c[i][j] = e[j] * inv + HC_EPS;
    }
    #pragma unroll
    for (int j = 0; j < HC; ++j) {
        const float cs = c[0][j] + c[1][j] + c[2][j] + c[3][j] + HC_EPS;
        const float inv = 1.0f / cs;
        c[0][j] *= inv; c[1][j] *= inv; c[2][j] *= inv; c[3][j] *= inv;
    }
    #pragma unroll
    for (int it = 0; it < 4; ++it) {
        #pragma unroll
        for (int i = 0; i < HC; ++i) {
            const float rsum = c[i][0] + c[i][1] + c[i][2] + c[i][3] + HC_EPS;
            const float inv = 1.0f / rsum;
            c[i][0] *= inv; c[i][1] *= inv; c[i][2] *= inv; c[i][3] *= inv;
        }
        #pragma unroll
        for (int j = 0; j < HC; ++j) {
            const float cs = c[0][j] + c[1][j] + c[2][j] + c[3][j] + HC_EPS;
            const float inv = 1.0f / cs;
            c[0][j] *= inv; c[1][j] *= inv; c[2][j] *= inv; c[3][j] *= inv;
        }
    }
    #pragma unroll
    for (int i = 0; i < HC; ++i)
        #pragma unroll
        for (int j = 0; j < HC; ++j)
            out[COMB_OFF + row * (HC * HC) + i * HC + j] = c[i][j];
}

extern "C" void kernel_launch(void* const* d_in, const int* in_sizes, int n_in,
                              void* d_out, int out_size, void* d_ws, size_t ws_size,
                              hipStream_t stream) {
    const float* hs    = (const float*)d_in[0];
    const float* fn    = (const float*)d_in[1];
    const float* base  = (const float*)d_in[2];
    const float* scale = (const float*)d_in[3];
    float* out = (float*)d_out;
    float* ws  = (float*)d_ws;   // 8192*32*32*4 B = 33.6 MB

    hyper_k1<<<KSPLIT * NSTREAM, THREADS1, 0, stream>>>(hs, fn, ws);  // 512 blocks
    hyper_k2<<<NROWS / 8, 256, 0, stream>>>(ws, base, scale, out);    // 1024 blocks
}

// Round 19
// 126.908 us; speedup vs baseline: 1.0529x; 1.0529x over previous
//
#include <hip/hip_runtime.h>
#include <hip/hip_bf16.h>
#include <math.h>
#include <stdint.h>

#define HC 4
#define DIM 16384                  // hc*hidden
#define MIXN 24
#define NROWS 8192                 // B*S
#define KSPLIT 32                  // k-slices
#define KSL 512                    // k per slice
#define NSTEPS 16                  // MFMA k-steps per slice
#define NSTREAM 8                  // row streams
#define ROWS_PER_STREAM 1024
#define NTILES 64                  // 16-row tiles per block
#define NBUF 2                     // s_a ring buffers
#define THREADS1 512
#define WREC 32                    // padded floats per (row, ks) record
#define HC_EPS 1e-5f
#define NORM_EPS 1e-6f

#define PRE_OFF 0
#define POST_OFF (NROWS * HC)
#define COMB_OFF (2 * NROWS * HC)

typedef float f32x4 __attribute__((ext_vector_type(4)));
typedef float accf4 __attribute__((ext_vector_type(4)));
typedef short bf16x8 __attribute__((ext_vector_type(8)));
typedef short bf16x4 __attribute__((ext_vector_type(4)));

__device__ __forceinline__ short f2bf(float x) {
    union { __hip_bfloat16 h; short s; } u;
    u.h = __float2bfloat16(x);
    return u.s;
}

// ---------------- kernel 1 ----------------
// R17's validated pipeline (contiguous 1KB A loads, 2 register ISSUE sets
// holding tiles t+2/t+3 in flight, swizzled fragment LDS) with ONE barrier
// per tile: the 8-wave sC reduce of tile t-1 runs concurrently with tile
// t's MFMA phase (sC double-buffered by tile parity). R16/17/18 A/Bs
// exonerated occupancy and depth; the 2-barrier serial tail is the last
// structural suspect.
__global__ __launch_bounds__(THREADS1) void hyper_k1(
    const float* __restrict__ hs,   // [NROWS][DIM]
    const float* __restrict__ fn,   // [MIXN][DIM]
    float* __restrict__ ws)         // [NROWS][KSPLIT][WREC]
{
    const int tid  = threadIdx.x;
    const int wave = tid >> 6;
    const int lane = tid & 63;
    const int l15  = lane & 15;
    const int kg   = lane >> 4;
    const int ks     = blockIdx.x & (KSPLIT - 1);
    const int stream = blockIdx.x >> 5;

    __shared__ __align__(16) short s_fn[2][NSTEPS][512];    // 32 KB B-fragments
    __shared__ __align__(16) short s_a[NBUF][NSTEPS][512];  // 32 KB A ring
    __shared__ float sC[2][8][400];                         // 25.6 KB partials (tile parity)

    // ---- fill s_fn (R15-18-validated 4-pass mapping for KSL=512) ----
    #pragma unroll 1
    for (int p = 0; p < 4; ++p) {
        const int idx  = p * THREADS1 + tid;
        const int kgf  = idx & 3;
        const int s    = (idx >> 2) & 15;
        const int c    = (idx >> 6) & 15;
        const int tile = idx >> 10;
        const int col  = tile ? (c + 8) : c;
        const float* g = fn + (size_t)col * DIM + ks * KSL + s * 32 + kgf * 8;
        const f32x4 v0 = *(const f32x4*)g;
        const f32x4 v1 = *(const f32x4*)(g + 4);
        bf16x8 b = { f2bf(v0.x), f2bf(v0.y), f2bf(v0.z), f2bf(v0.w),
                     f2bf(v1.x), f2bf(v1.y), f2bf(v1.z), f2bf(v1.w) };
        *(bf16x8*)&s_fn[tile][s][(kgf * 16 + c) * 8] = b;
    }
    __syncthreads();

    // stage-lane decomposition (R14-validated)
    const int st_slo = lane >> 3;
    const int st_kg  = (lane >> 1) & 3;
    const int st_e   = (lane & 1) * 4;
    const int sr0 = 2 * wave, sr1 = 2 * wave + 1;

    // reduce-lane mapping (tid < 400)
    const int red_rr = tid / 25, red_c = tid % 25;

    // two register ISSUE sets; set parity = tile & 1
    f32x4 RA0, RA1, RA2, RA3;
    f32x4 RB0, RB1, RB2, RB3;

#define ISSUE(P0, P1, P2, P3, T) do { \
    const float* g0 = hs + (size_t)(stream * ROWS_PER_STREAM + (T) * 16 + sr0) * DIM + ks * KSL; \
    const float* g1 = hs + (size_t)(stream * ROWS_PER_STREAM + (T) * 16 + sr1) * DIM + ks * KSL; \
    P0 = *(const f32x4*)(g0 +   0 + lane * 4); \
    P1 = *(const f32x4*)(g0 + 256 + lane * 4); \
    P2 = *(const f32x4*)(g1 +   0 + lane * 4); \
    P3 = *(const f32x4*)(g1 + 256 + lane * 4); \
} while (0)

#define WR1(BUF, Rj, r, j) do { \
    const int s_ = (j) * 8 + st_slo; \
    int byte_ = ((s_ * 64 + st_kg * 16 + (r)) * 16) + st_e * 2; \
    byte_ ^= ((s_ & 7) << 4); \
    bf16x4 v_ = { f2bf(Rj.x), f2bf(Rj.y), f2bf(Rj.z), f2bf(Rj.w) }; \
    *(bf16x4*)((char*)(&s_a[BUF][0][0]) + byte_) = v_; \
} while (0)

#define WRALL(BUF, P0, P1, P2, P3) do { \
    WR1(BUF, P0, sr0, 0); WR1(BUF, P1, sr0, 1); \
    WR1(BUF, P2, sr1, 0); WR1(BUF, P3, sr1, 1); \
} while (0)

    // reduce tile T's sC (parity T&1) and store to ws -- runs AFTER the
    // barrier of tile T+1, overlapped with tile T+1's compute.
#define REDUCE(T) do { \
    if (tid < 400) { \
        const int par_ = (T) & 1; \
        const float v_ = sC[par_][0][tid] + sC[par_][1][tid] \
                       + sC[par_][2][tid] + sC[par_][3][tid] \
                       + sC[par_][4][tid] + sC[par_][5][tid] \
                       + sC[par_][6][tid] + sC[par_][7][tid]; \
        const int row_ = stream * ROWS_PER_STREAM + (T) * 16 + red_rr; \
        ws[((size_t)row_ * KSPLIT + ks) * WREC + red_c] = v_; \
    } \
} while (0)

    // prologue: tiles 0,1 issued; tile 0 staged into buf 0; tile 2 issued
    ISSUE(RA0, RA1, RA2, RA3, 0);
    ISSUE(RB0, RB1, RB2, RB3, 1);
    WRALL(0, RA0, RA1, RA2, RA3);        // waits set A regs only (oldest)
    ISSUE(RA0, RA1, RA2, RA3, 2);

    int buf = 0;
    #pragma unroll 2
    for (int t = 0; t < NTILES; ++t) {
        // single barrier per tile: orders (a) WRALL(t) writes -> compute(t)
        // reads, (b) sC[t-1] writes -> REDUCE(t-1) reads, (c) REDUCE(t-2)
        // reads -> compute(t) overwrites of that parity (reads drained by
        // each wave's own lgkmcnt(0) before it passes the barrier).
        asm volatile("s_waitcnt lgkmcnt(0)" ::: "memory");
        __builtin_amdgcn_s_barrier();            // raw: in-flight loads survive
        __builtin_amdgcn_sched_barrier(0);

        // ---- reduce tile t-1 (overlaps this tile's compute) ----
        if (t > 0) REDUCE(t - 1);

        // ---- compute tile t -> sC[t&1] ----
        accf4 acc0 = {0.f, 0.f, 0.f, 0.f};
        accf4 acc1 = {0.f, 0.f, 0.f, 0.f};
        accf4 accS = {0.f, 0.f, 0.f, 0.f};
        #pragma unroll
        for (int i = 0; i < 2; ++i) {
            const int s = wave * 2 + i;
            int ab = ((s * 64 + lane) * 16) ^ ((s & 7) << 4);
            const bf16x8 af = *(const bf16x8*)((const char*)(&s_a[buf][0][0]) + ab);
            const bf16x8 b0 = *(const bf16x8*)&s_fn[0][s][lane * 8];
            const bf16x8 b1 = *(const bf16x8*)&s_fn[1][s][lane * 8];
            acc0 = __builtin_amdgcn_mfma_f32_16x16x32_bf16(af, b0, acc0, 0, 0, 0);
            acc1 = __builtin_amdgcn_mfma_f32_16x16x32_bf16(af, b1, acc1, 0, 0, 0);
            accS = __builtin_amdgcn_mfma_f32_16x16x32_bf16(af, af, accS, 0, 0, 0);
        }

        // per-wave partials -> sC[t&1] (C layout validated R11)
        {
            const int par = t & 1;
            #pragma unroll
            for (int i = 0; i < 4; ++i)
                sC[par][wave][(kg * 4 + i) * 25 + l15] = acc0[i];
            if (l15 >= 8) {
                #pragma unroll
                for (int i = 0; i < 4; ++i)
                    sC[par][wave][(kg * 4 + i) * 25 + l15 + 8] = acc1[i];
            }
            #pragma unroll
            for (int i = 0; i < 4; ++i)
                if (l15 == kg * 4 + i) sC[par][wave][l15 * 25 + 24] = accS[i];
        }

        // ---- WRALL(t+1) from older set, then ISSUE(t+3) into same set ----
        if (t + 1 < NTILES) {
            const int nbuf = buf ^ 1;
            if ((t & 1) == 0) {
                WRALL(nbuf, RB0, RB1, RB2, RB3);             // tile t+1 (set B)
                if (t + 3 < NTILES) ISSUE(RB0, RB1, RB2, RB3, t + 3);
            } else {
                WRALL(nbuf, RA0, RA1, RA2, RA3);             // tile t+1 (set A)
                if (t + 3 < NTILES) ISSUE(RA0, RA1, RA2, RA3, t + 3);
            }
        }
        buf ^= 1;
    }

    // epilogue: reduce the last tile
    asm volatile("s_waitcnt lgkmcnt(0)" ::: "memory");
    __builtin_amdgcn_s_barrier();
    REDUCE(NTILES - 1);
#undef ISSUE
#undef WR1
#undef WRALL
#undef REDUCE
}

// ---------------- kernel 2: parallel slice-reduce + epilogue ----------------
__global__ __launch_bounds__(256) void hyper_k2(
    const float* __restrict__ ws,
    const float* __restrict__ base,
    const float* __restrict__ scale,
    float* __restrict__ out)
{
    const int tid = threadIdx.x;
    const int row = blockIdx.x * 8 + (tid >> 5);     // 8 rows per block
    const int ks  = tid & 31;

    float v[25];
    const float* w = ws + ((size_t)row * KSPLIT + ks) * WREC;
    #pragma unroll
    for (int c = 0; c < 25; ++c) v[c] = w[c];

    #pragma unroll
    for (int off = 16; off >= 1; off >>= 1)
        #pragma unroll
        for (int c = 0; c < 25; ++c) v[c] += __shfl_xor(v[c], off, 32);

    if (ks != 0) return;

    const float rs = 1.0f / sqrtf(v[24] * (1.0f / (float)DIM) + NORM_EPS);
    const float s0 = scale[0], s1 = scale[1], s2 = scale[2];

    #pragma unroll
    for (int i = 0; i < HC; ++i) {
        const float z = v[i] * rs * s0 + base[i];
        out[PRE_OFF + row * HC + i] = 1.0f / (1.0f + expf(-z)) + HC_EPS;
    }
    #pragma unroll
    for (int i = 0; i < HC; ++i) {
        const float z = v[HC + i] * rs * s1 + base[HC + i];
        out[POST_OFF + row * HC + i] = 2.0f / (1.0f + expf(-z));
    }

    float c[HC][HC];
    #pragma unroll
    for (int i = 0; i < HC; ++i) {
        float l[HC];
        #pragma unroll
        for (int j = 0; j < HC; ++j)
            l[j] = v[2 * HC + i * HC + j] * rs * s2 + base[2 * HC + i * HC + j];
        const float mx = fmaxf(fmaxf(l[0], l[1]), fmaxf(l[2], l[3]));
        float e[HC];
        float sum = 0.0f;
        #pragma unroll
        for (int j = 0; j < HC; ++j) { e[j] = expf(l[j] - mx); sum += e[j]; }
        const float inv = 1.0f / sum;
        #pragma unroll
        for (int j = 0; j < HC; ++j) c[i][j] = e[j] * inv + HC_EPS;
    }
    #pragma unroll
    for (int j = 0; j < HC; ++j) {
        const float cs = c[0][j] + c[1][j] + c[2][j] + c[3][j] + HC_EPS;
        const float inv = 1.0f / cs;
        c[0][j] *= inv; c[1][j] *= inv; c[2][j] *= inv; c[3][j] *= inv;
    }
    #pragma unroll
    for (int it = 0; it < 4; ++it) {
        #pragma unroll
        for (int i = 0; i < HC; ++i) {
            const float rsum = c[i][0] + c[i][1] + c[i][2] + c[i][3] + HC_EPS;
            const float inv = 1.0f / rsum;
            c[i][0] *= inv; c[i][1] *= inv; c[i][2] *= inv; c[i][3] *= inv;
        }
        #pragma unroll
        for (int j = 0; j < HC; ++j) {
            const float cs = c[0][j] + c[1][j] + c[2][j] + c[3][j] + HC_EPS;
            const float inv = 1.0f / cs;
            c[0][j] *= inv; c[1][j] *= inv; c[2][j] *= inv; c[3][j] *= inv;
        }
    }
    #pragma unroll
    for (int i = 0; i < HC; ++i)
        #pragma unroll
        for (int j = 0; j < HC; ++j)
            out[COMB_OFF + row * (HC * HC) + i * HC + j] = c[i][j];
}

extern "C" void kernel_launch(void* const* d_in, const int* in_sizes, int n_in,
                              void* d_out, int out_size, void* d_ws, size_t ws_size,
                              hipStream_t stream) {
    const float* hs    = (const float*)d_in[0];
    const float* fn    = (const float*)d_in[1];
    const float* base  = (const float*)d_in[2];
    const float* scale = (const float*)d_in[3];
    float* out = (float*)d_out;
    float* ws  = (float*)d_ws;   // 8192*32*32*4 B = 33.6 MB

    hyper_k1<<<KSPLIT * NSTREAM, THREADS1, 0, stream>>>(hs, fn, ws);  // 256 blocks
    hyper_k2<<<NROWS / 8, 256, 0, stream>>>(ws, base, scale, out);    // 1024 blocks
}